// Round 1
// baseline (173.095 us; speedup 1.0000x reference)
//
#include <hip/hip_runtime.h>
#include <math.h>

// OLCNN: x(B,1,9,9) -> conv3x3(16) -> sigmoid (relu is no-op after sigmoid)
//        -> maxpool2x2 floor (7x7->3x3) -> "conv2" 16*3x3 -> 32, sigmoid
//        -> fc 32->4.  B = 131072, all fp32.
//
// One thread = one sample. Only x[0..7][0..7] is ever used (pool floor mode
// discards conv output rows/cols 6). Conv2 accumulation is folded into the
// conv1 channel loop (pooled[9] regs per channel, acc2[32] running).
// x staged via LDS (coalesced global reads, stride-65 pad => conflict-free
// per-thread readback). Weights read with wave-uniform indices from global
// (expect s_load scalarization).

#define BLOCK 128

__device__ __forceinline__ float fast_sigmoid(float s) {
    // 1/(1+e^-s); v_exp_f32 + v_rcp_f32, plenty of accuracy for 2e-2 absmax
    return __builtin_amdgcn_rcpf(1.0f + __expf(-s));
}

__global__ __launch_bounds__(BLOCK, 2) void olcnn_kernel(
    const float* __restrict__ xg,   // (B,81)
    const float* __restrict__ w1,   // (16,9)
    const float* __restrict__ b1,   // (16,)
    const float* __restrict__ w2,   // (32,144)
    const float* __restrict__ b2,   // (32,)
    const float* __restrict__ fcw,  // (4,32)
    const float* __restrict__ fcb,  // (4,)
    float* __restrict__ out)        // (B,4)
{
    __shared__ float lds_x[BLOCK * 65];   // 64 floats/sample, stride 65 (pad)

    const int tid = threadIdx.x;
    const long long block_base = (long long)blockIdx.x * BLOCK;
    const float* xsrc = xg + block_base * 81;

    // Coalesced stage of this block's 128*81 floats; keep only r<8 && c<8.
    for (int i = tid; i < BLOCK * 81; i += BLOCK) {
        float v = xsrc[i];
        int s = i / 81;
        int e = i - s * 81;
        int r = e / 9;
        int c = e - r * 9;
        if (r < 8 && c < 8) lds_x[s * 65 + r * 8 + c] = v;
    }
    __syncthreads();

    // Per-thread x registers (64). Lane stride 65 => bank-conflict-free.
    float xr[64];
    #pragma unroll
    for (int r = 0; r < 8; ++r)
        #pragma unroll
        for (int c = 0; c < 8; ++c)
            xr[r * 8 + c] = lds_x[tid * 65 + r * 8 + c];

    // conv2 accumulators, bias pre-loaded (uniform loads)
    float acc2[32];
    #pragma unroll
    for (int oc = 0; oc < 32; ++oc) acc2[oc] = b2[oc];

    for (int o = 0; o < 16; ++o) {
        float w[9];
        #pragma unroll
        for (int k = 0; k < 9; ++k) w[k] = w1[o * 9 + k];
        const float bb = b1[o];

        float pooled[9];
        #pragma unroll
        for (int pi = 0; pi < 3; ++pi) {
            #pragma unroll
            for (int pj = 0; pj < 3; ++pj) {
                float vmax;
                #pragma unroll
                for (int dh = 0; dh < 2; ++dh) {
                    #pragma unroll
                    for (int dw = 0; dw < 2; ++dw) {
                        const int h = 2 * pi + dh;
                        const int ww = 2 * pj + dw;
                        float s = bb;
                        #pragma unroll
                        for (int i = 0; i < 3; ++i)
                            #pragma unroll
                            for (int j = 0; j < 3; ++j)
                                s = fmaf(xr[(h + i) * 8 + (ww + j)],
                                         w[i * 3 + j], s);
                        float v = fast_sigmoid(s);
                        if (dh == 0 && dw == 0) vmax = v;
                        else vmax = fmaxf(vmax, v);
                    }
                }
                pooled[pi * 3 + pj] = vmax;
            }
        }

        // conv2 partial: d = o*9 + cell; w2 row-major (32,144) — 9 contiguous
        // floats per (oc,o), wave-uniform addresses.
        const float* w2row = w2 + o * 9;
        #pragma unroll
        for (int oc = 0; oc < 32; ++oc) {
            const float* wr = w2row + oc * 144;
            float a = acc2[oc];
            #pragma unroll
            for (int cell = 0; cell < 9; ++cell)
                a = fmaf(wr[cell], pooled[cell], a);
            acc2[oc] = a;
        }
    }

    // h2 = sigmoid(acc2); out = fc_w @ h2 + fc_b
    float r0 = fcb[0], r1 = fcb[1], r2 = fcb[2], r3 = fcb[3];
    #pragma unroll
    for (int oc = 0; oc < 32; ++oc) {
        float h = fast_sigmoid(acc2[oc]);
        r0 = fmaf(fcw[0 * 32 + oc], h, r0);
        r1 = fmaf(fcw[1 * 32 + oc], h, r1);
        r2 = fmaf(fcw[2 * 32 + oc], h, r2);
        r3 = fmaf(fcw[3 * 32 + oc], h, r3);
    }

    float4 res = make_float4(r0, r1, r2, r3);
    ((float4*)out)[block_base + tid] = res;
}

extern "C" void kernel_launch(void* const* d_in, const int* in_sizes, int n_in,
                              void* d_out, int out_size, void* d_ws, size_t ws_size,
                              hipStream_t stream) {
    const float* x   = (const float*)d_in[0];
    const float* w1  = (const float*)d_in[1];
    const float* b1  = (const float*)d_in[2];
    const float* w2  = (const float*)d_in[3];
    const float* b2  = (const float*)d_in[4];
    const float* fcw = (const float*)d_in[5];
    const float* fcb = (const float*)d_in[6];
    float* out = (float*)d_out;

    const int nB = in_sizes[0] / 81;      // 131072, divisible by BLOCK
    dim3 grid(nB / BLOCK), block(BLOCK);
    olcnn_kernel<<<grid, block, 0, stream>>>(x, w1, b1, w2, b2, fcw, fcb, out);
}

// Round 2
// 156.271 us; speedup vs baseline: 1.1077x; 1.1077x over previous
//
#include <hip/hip_runtime.h>
#include <math.h>

// OLCNN: x(B,1,9,9) -> conv3x3(16) -> sigmoid (relu no-op) -> maxpool2x2 floor
//        -> conv2 (16*3x3 -> 32) -> sigmoid -> fc 32->4.  B = 131072, fp32.
//
// Round 2 design:
//  * one thread = one sample (w1/w2/fc reads stay wave-uniform -> s_load,
//    scalar pipe, free w.r.t. VALU)
//  * sigmoid AFTER maxpool (exact: sigmoid monotonic, relu(sigmoid)=sigmoid)
//    -> 144+32 sigmoids/sample instead of 608
//  * log2(e) folded into w1/b1 (uniform scale once per channel) so
//    sigmoid = rcp(1 + exp2(-s)) with no per-element multiply
//  * NO LDS: each thread loads its 64 needed x floats (rows/cols 0..7;
//    pool floor-mode discards row/col 6 of the conv output) straight to
//    VGPRs. Per-lane contiguous dword streams; wave working set 20.7 KB
//    fits L1, same HBM line count as coalesced staging, zero barriers.
//  * o-loop kept rolled (full unroll ~80KB code, I$ thrash)

#define BLOCK 256
#define LOG2E 1.4426950408889634f

__device__ __forceinline__ float sig_from_scaled(float s2) {
    // input already scaled by log2e: sigmoid = 1/(1+2^-s2)
    return __builtin_amdgcn_rcpf(1.0f + __builtin_amdgcn_exp2f(-s2));
}

__device__ __forceinline__ float fast_sigmoid(float s) {
    return __builtin_amdgcn_rcpf(1.0f + __builtin_amdgcn_exp2f(-s * LOG2E));
}

__global__ __launch_bounds__(BLOCK) void olcnn_kernel(
    const float* __restrict__ xg,   // (B,81)
    const float* __restrict__ w1,   // (16,9)
    const float* __restrict__ b1,   // (16,)
    const float* __restrict__ w2,   // (32,144)
    const float* __restrict__ b2,   // (32,)
    const float* __restrict__ fcw,  // (4,32)
    const float* __restrict__ fcb,  // (4,)
    float* __restrict__ out)        // (B,4)
{
    const int t = blockIdx.x * BLOCK + threadIdx.x;
    const float* xs = xg + (long long)t * 81;

    // x[0..7][0..7] into registers (64 VGPRs)
    float xr[64];
    #pragma unroll
    for (int r = 0; r < 8; ++r)
        #pragma unroll
        for (int c = 0; c < 8; ++c)
            xr[r * 8 + c] = xs[r * 9 + c];

    // conv2 accumulators, bias preloaded (uniform s_loads)
    float acc2[32];
    #pragma unroll
    for (int oc = 0; oc < 32; ++oc) acc2[oc] = b2[oc];

    for (int o = 0; o < 16; ++o) {
        // per-channel weights, pre-scaled by log2e (uniform scalar math)
        float w[9];
        #pragma unroll
        for (int k = 0; k < 9; ++k) w[k] = w1[o * 9 + k] * LOG2E;
        const float bb = b1[o] * LOG2E;

        float pooled[9];
        #pragma unroll
        for (int pi = 0; pi < 3; ++pi) {
            #pragma unroll
            for (int pj = 0; pj < 3; ++pj) {
                float vmax;
                #pragma unroll
                for (int dh = 0; dh < 2; ++dh) {
                    #pragma unroll
                    for (int dw = 0; dw < 2; ++dw) {
                        const int h = 2 * pi + dh;
                        const int ww = 2 * pj + dw;
                        float s = bb;
                        #pragma unroll
                        for (int i = 0; i < 3; ++i)
                            #pragma unroll
                            for (int j = 0; j < 3; ++j)
                                s = fmaf(xr[(h + i) * 8 + (ww + j)],
                                         w[i * 3 + j], s);
                        if (dh == 0 && dw == 0) vmax = s;
                        else vmax = fmaxf(vmax, s);
                    }
                }
                // sigmoid once per pooled cell (max moved before sigmoid)
                pooled[pi * 3 + pj] = sig_from_scaled(vmax);
            }
        }

        // conv2 partial: feature d = o*9 + cell, w2 row-major (32,144);
        // wave-uniform addresses -> s_load
        const float* w2row = w2 + o * 9;
        #pragma unroll
        for (int oc = 0; oc < 32; ++oc) {
            const float* wr = w2row + oc * 144;
            float a = acc2[oc];
            #pragma unroll
            for (int cell = 0; cell < 9; ++cell)
                a = fmaf(wr[cell], pooled[cell], a);
            acc2[oc] = a;
        }
    }

    // h2 = sigmoid(acc2); out = fc_w @ h2 + fc_b
    float r0 = fcb[0], r1 = fcb[1], r2 = fcb[2], r3 = fcb[3];
    #pragma unroll
    for (int oc = 0; oc < 32; ++oc) {
        float h = fast_sigmoid(acc2[oc]);
        r0 = fmaf(fcw[0 * 32 + oc], h, r0);
        r1 = fmaf(fcw[1 * 32 + oc], h, r1);
        r2 = fmaf(fcw[2 * 32 + oc], h, r2);
        r3 = fmaf(fcw[3 * 32 + oc], h, r3);
    }

    ((float4*)out)[t] = make_float4(r0, r1, r2, r3);
}

extern "C" void kernel_launch(void* const* d_in, const int* in_sizes, int n_in,
                              void* d_out, int out_size, void* d_ws, size_t ws_size,
                              hipStream_t stream) {
    const float* x   = (const float*)d_in[0];
    const float* w1  = (const float*)d_in[1];
    const float* b1  = (const float*)d_in[2];
    const float* w2  = (const float*)d_in[3];
    const float* b2  = (const float*)d_in[4];
    const float* fcw = (const float*)d_in[5];
    const float* fcb = (const float*)d_in[6];
    float* out = (float*)d_out;

    const int nB = in_sizes[0] / 81;      // 131072, divisible by BLOCK
    dim3 grid(nB / BLOCK), block(BLOCK);
    olcnn_kernel<<<grid, block, 0, stream>>>(x, w1, b1, w2, b2, fcw, fcb, out);
}

// Round 3
// 144.646 us; speedup vs baseline: 1.1967x; 1.0804x over previous
//
#include <hip/hip_runtime.h>
#include <math.h>

// OLCNN: x(B,1,9,9) -> conv3x3(16) -> sigmoid (relu no-op) -> maxpool2x2 floor
//        -> conv2 (16*3x3 -> 32) -> sigmoid -> fc 32->4.  B = 131072, fp32.
//
// Round 3:
//  * __launch_bounds__(256, 2): grid is 512 blocks / 256 CU = 2 blocks/CU
//    = 2 waves/SIMD — occupancy is grid-pinned, so let the register
//    allocator use up to ~256 VGPRs and keep xr[64] RESIDENT (round 2's
//    VGPR=64 meant x was re-loaded from global in every channel iter —
//    the ~45% stall).
//  * one thread = one sample: all w1/w2/fc reads wave-uniform -> s_load
//    (scalar pipe, free w.r.t. VALU)
//  * sigmoid after maxpool (exact: monotonic), relu dropped (sigmoid>0)
//  * only x[0..7][0..7] read (pool floor mode discards conv row/col 6)

#define BLOCK 256
#define LOG2E 1.4426950408889634f

__device__ __forceinline__ float fast_sigmoid(float s) {
    // rcp(1 + 2^(-s*log2e)); exp2 neg folds into input modifier
    return __builtin_amdgcn_rcpf(1.0f + __builtin_amdgcn_exp2f(-s * LOG2E));
}

__global__ __launch_bounds__(BLOCK, 2) void olcnn_kernel(
    const float* __restrict__ xg,   // (B,81)
    const float* __restrict__ w1,   // (16,9)
    const float* __restrict__ b1,   // (16,)
    const float* __restrict__ w2,   // (32,144)
    const float* __restrict__ b2,   // (32,)
    const float* __restrict__ fcw,  // (4,32)
    const float* __restrict__ fcb,  // (4,)
    float* __restrict__ out)        // (B,4)
{
    const int t = blockIdx.x * BLOCK + threadIdx.x;
    const float* xs = xg + (long long)t * 81;

    // x[0..7][0..7] into registers (64 VGPRs, live across the whole kernel)
    float xr[64];
    #pragma unroll
    for (int r = 0; r < 8; ++r)
        #pragma unroll
        for (int c = 0; c < 8; ++c)
            xr[r * 8 + c] = xs[r * 9 + c];

    // conv2 accumulators, bias preloaded (uniform s_loads)
    float acc2[32];
    #pragma unroll
    for (int oc = 0; oc < 32; ++oc) acc2[oc] = b2[oc];

    for (int o = 0; o < 16; ++o) {
        float w[9];
        #pragma unroll
        for (int k = 0; k < 9; ++k) w[k] = w1[o * 9 + k];
        const float bb = b1[o];

        float pooled[9];
        #pragma unroll
        for (int pi = 0; pi < 3; ++pi) {
            #pragma unroll
            for (int pj = 0; pj < 3; ++pj) {
                float vmax;
                #pragma unroll
                for (int dh = 0; dh < 2; ++dh) {
                    #pragma unroll
                    for (int dw = 0; dw < 2; ++dw) {
                        const int h = 2 * pi + dh;
                        const int ww = 2 * pj + dw;
                        float s = bb;
                        #pragma unroll
                        for (int i = 0; i < 3; ++i)
                            #pragma unroll
                            for (int j = 0; j < 3; ++j)
                                s = fmaf(xr[(h + i) * 8 + (ww + j)],
                                         w[i * 3 + j], s);
                        if (dh == 0 && dw == 0) vmax = s;
                        else vmax = fmaxf(vmax, s);
                    }
                }
                // one sigmoid per pooled cell (max hoisted before sigmoid)
                pooled[pi * 3 + pj] = fast_sigmoid(vmax);
            }
        }

        // conv2 partial: feature d = o*9 + cell, w2 row-major (32,144);
        // wave-uniform addresses -> s_load
        const float* w2row = w2 + o * 9;
        #pragma unroll
        for (int oc = 0; oc < 32; ++oc) {
            const float* wr = w2row + oc * 144;
            float a = acc2[oc];
            #pragma unroll
            for (int cell = 0; cell < 9; ++cell)
                a = fmaf(wr[cell], pooled[cell], a);
            acc2[oc] = a;
        }
    }

    // h2 = sigmoid(acc2); out = fc_w @ h2 + fc_b
    float r0 = fcb[0], r1 = fcb[1], r2 = fcb[2], r3 = fcb[3];
    #pragma unroll
    for (int oc = 0; oc < 32; ++oc) {
        float h = fast_sigmoid(acc2[oc]);
        r0 = fmaf(fcw[0 * 32 + oc], h, r0);
        r1 = fmaf(fcw[1 * 32 + oc], h, r1);
        r2 = fmaf(fcw[2 * 32 + oc], h, r2);
        r3 = fmaf(fcw[3 * 32 + oc], h, r3);
    }

    ((float4*)out)[t] = make_float4(r0, r1, r2, r3);
}

extern "C" void kernel_launch(void* const* d_in, const int* in_sizes, int n_in,
                              void* d_out, int out_size, void* d_ws, size_t ws_size,
                              hipStream_t stream) {
    const float* x   = (const float*)d_in[0];
    const float* w1  = (const float*)d_in[1];
    const float* b1  = (const float*)d_in[2];
    const float* w2  = (const float*)d_in[3];
    const float* b2  = (const float*)d_in[4];
    const float* fcw = (const float*)d_in[5];
    const float* fcb = (const float*)d_in[6];
    float* out = (float*)d_out;

    const int nB = in_sizes[0] / 81;      // 131072, divisible by BLOCK
    dim3 grid(nB / BLOCK), block(BLOCK);
    olcnn_kernel<<<grid, block, 0, stream>>>(x, w1, b1, w2, b2, fcw, fcb, out);
}